// Round 1
// baseline (619.009 us; speedup 1.0000x reference)
//
#include <hip/hip_runtime.h>
#include <hip/hip_bf16.h>

#define NN 50000
#define NE 800000
#define KD 768
#define HIDD 128
#define NC 6

// ---------------- CSR build ----------------

__global__ void count_kernel(const int* __restrict__ ei, int* __restrict__ cnt) {
    int e = blockIdx.x * blockDim.x + threadIdx.x;
    if (e >= NE) return;
    int d = ei[NE + e];
    d = min(max(d, 0), NN - 1);
    atomicAdd(&cnt[d], 1);
}

// 49 blocks x 256 threads, 4 elems/thread (1024/block)
__global__ void scan_blocks_kernel(const int* __restrict__ cnt, int* __restrict__ row_ptr,
                                   float* __restrict__ dinv, int* __restrict__ bsum) {
    __shared__ int s[256];
    int t = threadIdx.x;
    int base = blockIdx.x * 1024 + t * 4;
    int v[4];
    int sum = 0;
#pragma unroll
    for (int j = 0; j < 4; ++j) {
        int i = base + j;
        v[j] = (i < NN) ? cnt[i] : 0;
        sum += v[j];
    }
    s[t] = sum;
    __syncthreads();
    for (int off = 1; off < 256; off <<= 1) {
        int val = (t >= off) ? s[t - off] : 0;
        __syncthreads();
        s[t] += val;
        __syncthreads();
    }
    int excl = s[t] - sum;      // exclusive prefix of this thread's chunk
    int total = s[255];
    if (t == 0) bsum[blockIdx.x] = total;
    int run = excl;
#pragma unroll
    for (int j = 0; j < 4; ++j) {
        int i = base + j;
        if (i < NN) {
            row_ptr[i] = run;
            dinv[i] = rsqrtf((float)(v[j] + 1));  // deg = indeg + self-loop
            run += v[j];
        }
    }
}

__global__ void scan_sums_kernel(int* __restrict__ bsum, int* __restrict__ row_ptr) {
    __shared__ int s[64];
    int t = threadIdx.x;
    int v = (t < 49) ? bsum[t] : 0;
    s[t] = v;
    __syncthreads();
    for (int off = 1; off < 64; off <<= 1) {
        int val = (t >= off) ? s[t - off] : 0;
        __syncthreads();
        s[t] += val;
        __syncthreads();
    }
    if (t < 49) bsum[t] = s[t] - v;      // exclusive block offsets
    if (t == 63) row_ptr[NN] = s[63];    // total edge count
}

__global__ void scan_add_kernel(int* __restrict__ row_ptr, int* __restrict__ cursor,
                                const int* __restrict__ bsum) {
    int i = blockIdx.x * blockDim.x + threadIdx.x;
    if (i >= NN) return;
    int r = row_ptr[i] + bsum[i >> 10];
    row_ptr[i] = r;
    cursor[i] = r;
}

__global__ void fill_kernel(const int* __restrict__ ei, int* __restrict__ cursor,
                            int* __restrict__ col) {
    int e = blockIdx.x * blockDim.x + threadIdx.x;
    if (e >= NE) return;
    int sidx = ei[e];
    int d = ei[NE + e];
    sidx = min(max(sidx, 0), NN - 1);
    d = min(max(d, 0), NN - 1);
    int pos = atomicAdd(&cursor[d], 1);
    col[pos] = sidx;
}

// ---------------- fp32 tiled GEMM: out[r][c] = dinv[r] * sum_k A[r][k] W[k][c] ----------------
// Output N fixed at 128. Block computes 64 rows x 128 cols; 256 threads, 8x4 acc each.

template <int K>
__global__ __launch_bounds__(256) void gemm_kernel(const float* __restrict__ A,
                                                   const float* __restrict__ W,
                                                   const float* __restrict__ dinv,
                                                   float* __restrict__ out, int M) {
    __shared__ float As[64][32];
    __shared__ float Bs[32][128];
    int t = threadIdx.x;
    int tc = t & 31;   // col group (4 cols)
    int tr = t >> 5;   // row group (8 rows)
    int row0 = blockIdx.x * 64;
    float acc[8][4] = {};
    for (int k0 = 0; k0 < K; k0 += 32) {
        // stage A tile: 64x32
#pragma unroll
        for (int i = 0; i < 8; ++i) {
            int e = t + i * 256;
            int r = e >> 5, k = e & 31;
            int gr = row0 + r;
            As[r][k] = (gr < M) ? A[(size_t)gr * K + k0 + k] : 0.f;
        }
        // stage B tile: 32x128
#pragma unroll
        for (int i = 0; i < 16; ++i) {
            int e = t + i * 256;
            int kr = e >> 7, c = e & 127;
            Bs[kr][c] = W[(size_t)(k0 + kr) * 128 + c];
        }
        __syncthreads();
#pragma unroll
        for (int kk = 0; kk < 32; ++kk) {
            float4 b = *(const float4*)&Bs[kk][tc * 4];
#pragma unroll
            for (int i = 0; i < 8; ++i) {
                float a = As[tr * 8 + i][kk];
                acc[i][0] += a * b.x;
                acc[i][1] += a * b.y;
                acc[i][2] += a * b.z;
                acc[i][3] += a * b.w;
            }
        }
        __syncthreads();
    }
#pragma unroll
    for (int i = 0; i < 8; ++i) {
        int row = row0 + tr * 8 + i;
        if (row < M) {
            float d = dinv[row];
            float4 o = make_float4(acc[i][0] * d, acc[i][1] * d, acc[i][2] * d, acc[i][3] * d);
            *(float4*)&out[(size_t)row * 128 + tc * 4] = o;
        }
    }
}

// ---------------- CSR aggregation: out[i] = relu(dinv[i]*(hs[i] + sum_j hs[col]) + b) ----------------
// one wave per node, float2 per lane

__global__ void agg_kernel(const float* __restrict__ hs, const int* __restrict__ row_ptr,
                           const int* __restrict__ col, const float* __restrict__ dinv,
                           const float* __restrict__ bias, float* __restrict__ out) {
    int wv = threadIdx.x >> 6;
    int l = threadIdx.x & 63;
    int i = blockIdx.x * 4 + wv;
    if (i >= NN) return;
    float2 acc = *(const float2*)&hs[(size_t)i * 128 + 2 * l];  // self-loop term
    int e0 = row_ptr[i], e1 = row_ptr[i + 1];
    for (int e = e0; e < e1; ++e) {
        int j = col[e];
        float2 v = *(const float2*)&hs[(size_t)j * 128 + 2 * l];
        acc.x += v.x;
        acc.y += v.y;
    }
    float d = dinv[i];
    float ox = fmaxf(acc.x * d + bias[2 * l], 0.f);
    float oy = fmaxf(acc.y * d + bias[2 * l + 1], 0.f);
    *(float2*)&out[(size_t)i * 128 + 2 * l] = make_float2(ox, oy);
}

// ---------------- heads: two 128x6 matvecs + log_softmax ----------------

__global__ void heads_kernel(const float* __restrict__ h, const float* __restrict__ Wi,
                             const float* __restrict__ bi, const float* __restrict__ Wl,
                             const float* __restrict__ bl, float* __restrict__ out) {
    __shared__ float sh[4][128];
    __shared__ float sl[4][12];
    int wv = threadIdx.x >> 6;
    int l = threadIdx.x & 63;
    int i = blockIdx.x * 4 + wv;
    float2 v = *(const float2*)&h[(size_t)i * 128 + 2 * l];
    sh[wv][2 * l] = v.x;
    sh[wv][2 * l + 1] = v.y;
    __syncthreads();
    if (l < 12) {
        int head = l / 6, c = l % 6;
        const float* W = head ? Wl : Wi;
        float acc = head ? bl[c] : bi[c];
#pragma unroll 8
        for (int k = 0; k < 128; ++k) acc += sh[wv][k] * W[k * 6 + c];
        sl[wv][l] = acc;
    }
    __syncthreads();
    if (l < 12) {
        int head = l / 6, c = l % 6;
        const float* g = &sl[wv][head * 6];
        float m = g[0];
#pragma unroll
        for (int c2 = 1; c2 < 6; ++c2) m = fmaxf(m, g[c2]);
        float s = 0.f;
#pragma unroll
        for (int c2 = 0; c2 < 6; ++c2) s += expf(g[c2] - m);
        float r = sl[wv][l] - m - logf(s);
        out[(size_t)head * NN * NC + (size_t)i * NC + c] = r;
    }
}

extern "C" void kernel_launch(void* const* d_in, const int* in_sizes, int n_in,
                              void* d_out, int out_size, void* d_ws, size_t ws_size,
                              hipStream_t stream) {
    const float* x  = (const float*)d_in[0];
    const int*   ei = (const int*)d_in[1];
    const float* W1 = (const float*)d_in[2];
    const float* b1 = (const float*)d_in[3];
    const float* W2 = (const float*)d_in[4];
    const float* b2 = (const float*)d_in[5];
    const float* Wi = (const float*)d_in[6];
    const float* bi = (const float*)d_in[7];
    const float* Wl = (const float*)d_in[8];
    const float* bl = (const float*)d_in[9];
    float* out = (float*)d_out;

    uint8_t* p = (uint8_t*)d_ws;
    auto alloc = [&](size_t bytes) {
        void* r = (void*)p;
        p += (bytes + 255) / 256 * 256;
        return r;
    };
    int* row_ptr = (int*)alloc((NN + 1) * sizeof(int));
    int* cursor  = (int*)alloc(NN * sizeof(int));      // doubles as cnt
    int* col     = (int*)alloc(NE * sizeof(int));
    int* bsum    = (int*)alloc(64 * sizeof(int));
    float* dinv  = (float*)alloc(NN * sizeof(float));
    float* bufA  = (float*)alloc((size_t)NN * HIDD * sizeof(float));
    float* bufB  = (float*)alloc((size_t)NN * HIDD * sizeof(float));

    hipMemsetAsync(cursor, 0, NN * sizeof(int), stream);
    count_kernel<<<(NE + 255) / 256, 256, 0, stream>>>(ei, cursor);
    scan_blocks_kernel<<<49, 256, 0, stream>>>(cursor, row_ptr, dinv, bsum);
    scan_sums_kernel<<<1, 64, 0, stream>>>(bsum, row_ptr);
    scan_add_kernel<<<(NN + 255) / 256, 256, 0, stream>>>(row_ptr, cursor, bsum);
    fill_kernel<<<(NE + 255) / 256, 256, 0, stream>>>(ei, cursor, col);

    // layer 1: hs = (x@W1)*dinv ; h1 = relu(dinv*(gather-sum) + b1)
    gemm_kernel<KD><<<(NN + 63) / 64, 256, 0, stream>>>(x, W1, dinv, bufA, NN);
    agg_kernel<<<NN / 4, 256, 0, stream>>>(bufA, row_ptr, col, dinv, b1, bufB);
    // layer 2
    gemm_kernel<HIDD><<<(NN + 63) / 64, 256, 0, stream>>>(bufB, W2, dinv, bufA, NN);
    agg_kernel<<<NN / 4, 256, 0, stream>>>(bufA, row_ptr, col, dinv, b2, bufB);
    // heads
    heads_kernel<<<NN / 4, 256, 0, stream>>>(bufB, Wi, bi, Wl, bl, out);
}

// Round 2
// 323.987 us; speedup vs baseline: 1.9106x; 1.9106x over previous
//
#include <hip/hip_runtime.h>
#include <hip/hip_bf16.h>

#define NN 50000
#define NE 800000
#define KD 768
#define HIDD 128
#define NC 6

typedef __attribute__((ext_vector_type(8))) short bf16x8;
typedef __attribute__((ext_vector_type(4))) float f32x4;

__device__ __forceinline__ ushort f2bf(float f) {
    union { float f; unsigned u; } v; v.f = f;
    unsigned u = v.u + 0x7FFF + ((v.u >> 16) & 1);   // round-to-nearest-even
    return (ushort)(u >> 16);
}
__device__ __forceinline__ float bf2f(ushort h) {
    union { unsigned u; float f; } v; v.u = ((unsigned)h) << 16;
    return v.f;
}

// ---------------- CSR build ----------------

__global__ void count_kernel(const int* __restrict__ ei, int* __restrict__ cnt) {
    int e = blockIdx.x * blockDim.x + threadIdx.x;
    if (e >= NE) return;
    int d = ei[NE + e];
    d = min(max(d, 0), NN - 1);
    atomicAdd(&cnt[d], 1);
}

__global__ void scan_blocks_kernel(const int* __restrict__ cnt, int* __restrict__ row_ptr,
                                   float* __restrict__ dinv, int* __restrict__ bsum) {
    __shared__ int s[256];
    int t = threadIdx.x;
    int base = blockIdx.x * 1024 + t * 4;
    int v[4];
    int sum = 0;
#pragma unroll
    for (int j = 0; j < 4; ++j) {
        int i = base + j;
        v[j] = (i < NN) ? cnt[i] : 0;
        sum += v[j];
    }
    s[t] = sum;
    __syncthreads();
    for (int off = 1; off < 256; off <<= 1) {
        int val = (t >= off) ? s[t - off] : 0;
        __syncthreads();
        s[t] += val;
        __syncthreads();
    }
    int excl = s[t] - sum;
    int total = s[255];
    if (t == 0) bsum[blockIdx.x] = total;
    int run = excl;
#pragma unroll
    for (int j = 0; j < 4; ++j) {
        int i = base + j;
        if (i < NN) {
            row_ptr[i] = run;
            dinv[i] = rsqrtf((float)(v[j] + 1));
            run += v[j];
        }
    }
}

__global__ void scan_sums_kernel(int* __restrict__ bsum, int* __restrict__ row_ptr) {
    __shared__ int s[64];
    int t = threadIdx.x;
    int v = (t < 49) ? bsum[t] : 0;
    s[t] = v;
    __syncthreads();
    for (int off = 1; off < 64; off <<= 1) {
        int val = (t >= off) ? s[t - off] : 0;
        __syncthreads();
        s[t] += val;
        __syncthreads();
    }
    if (t < 49) bsum[t] = s[t] - v;
    if (t == 63) row_ptr[NN] = s[63];
}

__global__ void scan_add_kernel(int* __restrict__ row_ptr, int* __restrict__ cursor,
                                const int* __restrict__ bsum) {
    int i = blockIdx.x * blockDim.x + threadIdx.x;
    if (i >= NN) return;
    int r = row_ptr[i] + bsum[i >> 10];
    row_ptr[i] = r;
    cursor[i] = r;
}

__global__ void fill_kernel(const int* __restrict__ ei, int* __restrict__ cursor,
                            int* __restrict__ col) {
    int e = blockIdx.x * blockDim.x + threadIdx.x;
    if (e >= NE) return;
    int sidx = ei[e];
    int d = ei[NE + e];
    sidx = min(max(sidx, 0), NN - 1);
    d = min(max(d, 0), NN - 1);
    int pos = atomicAdd(&cursor[d], 1);
    col[pos] = sidx;
}

// ---------------- weight prep: WT1[c][k] = bf16(W1[k][c]), WT2 likewise ----------------

__global__ void prep_wt(const float* __restrict__ W1, const float* __restrict__ W2,
                        ushort* __restrict__ WT1, ushort* __restrict__ WT2) {
    int i = blockIdx.x * blockDim.x + threadIdx.x;
    if (i < KD * HIDD) {
        int c = i / KD, k = i % KD;
        WT1[i] = f2bf(W1[(size_t)k * HIDD + c]);
    } else if (i < KD * HIDD + HIDD * HIDD) {
        int j = i - KD * HIDD;
        int c = j / HIDD, k = j % HIDD;
        WT2[j] = f2bf(W2[(size_t)k * HIDD + c]);
    }
}

// ---------------- MFMA GEMM: out[r][c] = bf16(dinv[r] * sum_k A[r][k] W[k][c]) ----------------
// 128x128 tile, BK=64, 4 waves (2x2), wave tile 64x64 = 4x4 frags of 16x16x32.
// LDS XOR-swizzle: 16B granule index ^= (row & 7)  (both write and read sides).

template <int KTOT, bool ABF16>
__global__ __launch_bounds__(256) void mfma_gemm(const void* __restrict__ Ap,
                                                 const ushort* __restrict__ WT,
                                                 const float* __restrict__ dinv,
                                                 ushort* __restrict__ out, int M) {
    __shared__ ushort As[128 * 64];
    __shared__ ushort Bs[128 * 64];
    int t = threadIdx.x;
    int lane = t & 63;
    int wid = t >> 6;
    int wr = wid >> 1, wc = wid & 1;
    int row0 = blockIdx.x * 128;
    f32x4 acc[4][4] = {};

    for (int k0 = 0; k0 < KTOT; k0 += 64) {
        // ---- stage A (convert fp32->bf16 on the fly when needed) ----
        if (ABF16) {
            const ushort* A = (const ushort*)Ap;
#pragma unroll
            for (int it = 0; it < 4; ++it) {
                int r = (t >> 3) + it * 32;
                int g = t & 7;
                int gr = row0 + r;
                bf16x8 v = {};
                if (gr < M) v = *(const bf16x8*)&A[(size_t)gr * KTOT + k0 + g * 8];
                *(bf16x8*)&As[r * 64 + ((g ^ (r & 7)) * 8)] = v;
            }
        } else {
            const float* A = (const float*)Ap;
#pragma unroll
            for (int it = 0; it < 8; ++it) {
                int r = (t >> 4) + it * 16;
                int k4 = t & 15;
                int gr = row0 + r;
                float4 v = make_float4(0.f, 0.f, 0.f, 0.f);
                if (gr < M) v = *(const float4*)&A[(size_t)gr * KTOT + k0 + k4 * 4];
                ushort4 w;
                w.x = f2bf(v.x); w.y = f2bf(v.y); w.z = f2bf(v.z); w.w = f2bf(v.w);
                int g = k4 >> 1, half = k4 & 1;
                *(ushort4*)&As[r * 64 + ((g ^ (r & 7)) * 8) + half * 4] = w;
            }
        }
        // ---- stage B from WT[c][k] (already bf16, pre-transposed) ----
#pragma unroll
        for (int it = 0; it < 4; ++it) {
            int c = (t >> 3) + it * 32;
            int g = t & 7;
            bf16x8 v = *(const bf16x8*)&WT[(size_t)c * KTOT + k0 + g * 8];
            *(bf16x8*)&Bs[c * 64 + ((g ^ (c & 7)) * 8)] = v;
        }
        __syncthreads();
#pragma unroll
        for (int h = 0; h < 2; ++h) {
            bf16x8 a[4], b[4];
#pragma unroll
            for (int m = 0; m < 4; ++m) {
                int r = wr * 64 + m * 16 + (lane & 15);
                int g = (h * 4 + (lane >> 4)) ^ (r & 7);
                a[m] = *(const bf16x8*)&As[r * 64 + g * 8];
            }
#pragma unroll
            for (int n = 0; n < 4; ++n) {
                int c = wc * 64 + n * 16 + (lane & 15);
                int g = (h * 4 + (lane >> 4)) ^ (c & 7);
                b[n] = *(const bf16x8*)&Bs[c * 64 + g * 8];
            }
#pragma unroll
            for (int m = 0; m < 4; ++m)
#pragma unroll
                for (int n = 0; n < 4; ++n)
                    acc[m][n] = __builtin_amdgcn_mfma_f32_16x16x32_bf16(a[m], b[n], acc[m][n], 0, 0, 0);
        }
        __syncthreads();
    }
    // epilogue: D layout col=lane&15, row=(lane>>4)*4+reg (m89-verified)
#pragma unroll
    for (int m = 0; m < 4; ++m) {
#pragma unroll
        for (int reg = 0; reg < 4; ++reg) {
            int row = row0 + wr * 64 + m * 16 + (lane >> 4) * 4 + reg;
            if (row < M) {
                float d = dinv[row];
#pragma unroll
                for (int n = 0; n < 4; ++n) {
                    int colg = wc * 64 + n * 16 + (lane & 15);
                    out[(size_t)row * 128 + colg] = f2bf(acc[m][n][reg] * d);
                }
            }
        }
    }
}

// ---------------- CSR aggregation (bf16 in/out, fp32 accum) ----------------
// out[i] = bf16(relu(dinv[i]*(hs[i] + sum_j hs[col]) + b)); one wave per node.

__global__ void agg_bf_kernel(const ushort* __restrict__ hs, const int* __restrict__ row_ptr,
                              const int* __restrict__ col, const float* __restrict__ dinv,
                              const float* __restrict__ bias, ushort* __restrict__ out) {
    int wv = threadIdx.x >> 6;
    int l = threadIdx.x & 63;
    int i = blockIdx.x * 4 + wv;
    unsigned v0 = *(const unsigned*)&hs[(size_t)i * 128 + 2 * l];
    float ax = bf2f((ushort)(v0 & 0xffff));
    float ay = bf2f((ushort)(v0 >> 16));
    int e0 = row_ptr[i], e1 = row_ptr[i + 1];
    int e = e0;
    for (; e + 4 <= e1; e += 4) {
        int j0 = col[e], j1 = col[e + 1], j2 = col[e + 2], j3 = col[e + 3];
        unsigned w0 = *(const unsigned*)&hs[(size_t)j0 * 128 + 2 * l];
        unsigned w1 = *(const unsigned*)&hs[(size_t)j1 * 128 + 2 * l];
        unsigned w2 = *(const unsigned*)&hs[(size_t)j2 * 128 + 2 * l];
        unsigned w3 = *(const unsigned*)&hs[(size_t)j3 * 128 + 2 * l];
        ax += bf2f((ushort)(w0 & 0xffff)) + bf2f((ushort)(w1 & 0xffff)) +
              bf2f((ushort)(w2 & 0xffff)) + bf2f((ushort)(w3 & 0xffff));
        ay += bf2f((ushort)(w0 >> 16)) + bf2f((ushort)(w1 >> 16)) +
              bf2f((ushort)(w2 >> 16)) + bf2f((ushort)(w3 >> 16));
    }
    for (; e < e1; ++e) {
        int j = col[e];
        unsigned w = *(const unsigned*)&hs[(size_t)j * 128 + 2 * l];
        ax += bf2f((ushort)(w & 0xffff));
        ay += bf2f((ushort)(w >> 16));
    }
    float d = dinv[i];
    float ox = fmaxf(fmaf(ax, d, bias[2 * l]), 0.f);
    float oy = fmaxf(fmaf(ay, d, bias[2 * l + 1]), 0.f);
    unsigned o = (unsigned)f2bf(ox) | ((unsigned)f2bf(oy) << 16);
    *(unsigned*)&out[(size_t)i * 128 + 2 * l] = o;
}

// ---------------- heads: two 128x6 matvecs + log_softmax ----------------

__global__ void heads_kernel(const ushort* __restrict__ h, const float* __restrict__ Wi,
                             const float* __restrict__ bi, const float* __restrict__ Wl,
                             const float* __restrict__ bl, float* __restrict__ out) {
    __shared__ float sh[4][128];
    __shared__ float sl[4][12];
    int wv = threadIdx.x >> 6;
    int l = threadIdx.x & 63;
    int i = blockIdx.x * 4 + wv;
    unsigned v = *(const unsigned*)&h[(size_t)i * 128 + 2 * l];
    sh[wv][2 * l] = bf2f((ushort)(v & 0xffff));
    sh[wv][2 * l + 1] = bf2f((ushort)(v >> 16));
    __syncthreads();
    if (l < 12) {
        int head = l / 6, c = l % 6;
        const float* W = head ? Wl : Wi;
        float acc = head ? bl[c] : bi[c];
#pragma unroll 8
        for (int k = 0; k < 128; ++k) acc += sh[wv][k] * W[k * 6 + c];
        sl[wv][l] = acc;
    }
    __syncthreads();
    if (l < 12) {
        int head = l / 6, c = l % 6;
        const float* g = &sl[wv][head * 6];
        float m = g[0];
#pragma unroll
        for (int c2 = 1; c2 < 6; ++c2) m = fmaxf(m, g[c2]);
        float s = 0.f;
#pragma unroll
        for (int c2 = 0; c2 < 6; ++c2) s += expf(g[c2] - m);
        float r = sl[wv][l] - m - logf(s);
        out[(size_t)head * NN * NC + (size_t)i * NC + c] = r;
    }
}

extern "C" void kernel_launch(void* const* d_in, const int* in_sizes, int n_in,
                              void* d_out, int out_size, void* d_ws, size_t ws_size,
                              hipStream_t stream) {
    const float* x  = (const float*)d_in[0];
    const int*   ei = (const int*)d_in[1];
    const float* W1 = (const float*)d_in[2];
    const float* b1 = (const float*)d_in[3];
    const float* W2 = (const float*)d_in[4];
    const float* b2 = (const float*)d_in[5];
    const float* Wi = (const float*)d_in[6];
    const float* bi = (const float*)d_in[7];
    const float* Wl = (const float*)d_in[8];
    const float* bl = (const float*)d_in[9];
    float* out = (float*)d_out;

    uint8_t* p = (uint8_t*)d_ws;
    auto alloc = [&](size_t bytes) {
        void* r = (void*)p;
        p += (bytes + 255) / 256 * 256;
        return r;
    };
    int* row_ptr = (int*)alloc((NN + 1) * sizeof(int));
    int* cursor  = (int*)alloc(NN * sizeof(int));
    int* col     = (int*)alloc(NE * sizeof(int));
    int* bsum    = (int*)alloc(64 * sizeof(int));
    float* dinv  = (float*)alloc(NN * sizeof(float));
    ushort* WT1  = (ushort*)alloc((size_t)KD * HIDD * sizeof(ushort));
    ushort* WT2  = (ushort*)alloc((size_t)HIDD * HIDD * sizeof(ushort));
    ushort* bufA = (ushort*)alloc((size_t)NN * HIDD * sizeof(ushort));
    ushort* bufB = (ushort*)alloc((size_t)NN * HIDD * sizeof(ushort));

    hipMemsetAsync(cursor, 0, NN * sizeof(int), stream);
    count_kernel<<<(NE + 255) / 256, 256, 0, stream>>>(ei, cursor);
    scan_blocks_kernel<<<49, 256, 0, stream>>>(cursor, row_ptr, dinv, bsum);
    scan_sums_kernel<<<1, 64, 0, stream>>>(bsum, row_ptr);
    scan_add_kernel<<<(NN + 255) / 256, 256, 0, stream>>>(row_ptr, cursor, bsum);
    fill_kernel<<<(NE + 255) / 256, 256, 0, stream>>>(ei, cursor, col);
    prep_wt<<<(KD * HIDD + HIDD * HIDD + 255) / 256, 256, 0, stream>>>(W1, W2, WT1, WT2);

    const int grid = (NN + 127) / 128;
    // layer 1: hs = bf16(dinv*(x@W1)) ; h1 = bf16(relu(dinv*gather + b1))
    mfma_gemm<KD, false><<<grid, 256, 0, stream>>>(x, WT1, dinv, bufA, NN);
    agg_bf_kernel<<<NN / 4, 256, 0, stream>>>(bufA, row_ptr, col, dinv, b1, bufB);
    // layer 2
    mfma_gemm<HIDD, true><<<grid, 256, 0, stream>>>(bufB, WT2, dinv, bufA, NN);
    agg_bf_kernel<<<NN / 4, 256, 0, stream>>>(bufA, row_ptr, col, dinv, b2, bufB);
    // heads
    heads_kernel<<<NN / 4, 256, 0, stream>>>(bufB, Wi, bi, Wl, bl, out);
}

// Round 3
// 245.424 us; speedup vs baseline: 2.5222x; 1.3201x over previous
//
#include <hip/hip_runtime.h>
#include <hip/hip_bf16.h>

#define NN 50000
#define NE 800000
#define KD 768
#define HIDD 128
#define NC 6

typedef __attribute__((ext_vector_type(8))) short bf16x8;
typedef __attribute__((ext_vector_type(4))) float f32x4;

__device__ __forceinline__ ushort f2bf(float f) {
    union { float f; unsigned u; } v; v.f = f;
    unsigned u = v.u + 0x7FFF + ((v.u >> 16) & 1);   // round-to-nearest-even
    return (ushort)(u >> 16);
}
__device__ __forceinline__ float bf2f(ushort h) {
    union { unsigned u; float f; } v; v.u = ((unsigned)h) << 16;
    return v.f;
}
__device__ __forceinline__ void gll16(const void* g, void* l) {
    __builtin_amdgcn_global_load_lds((const __attribute__((address_space(1))) void*)g,
                                     (__attribute__((address_space(3))) void*)l, 16, 0, 0);
}

// ---------------- CSR build ----------------

__global__ void count_kernel(const int* __restrict__ ei, int* __restrict__ cnt) {
    int e = blockIdx.x * blockDim.x + threadIdx.x;
    if (e >= NE) return;
    int d = ei[NE + e];
    d = min(max(d, 0), NN - 1);
    atomicAdd(&cnt[d], 1);
}

__global__ void scan_blocks_kernel(const int* __restrict__ cnt, int* __restrict__ row_ptr,
                                   float* __restrict__ dinv, int* __restrict__ bsum) {
    __shared__ int s[256];
    int t = threadIdx.x;
    int base = blockIdx.x * 1024 + t * 4;
    int v[4];
    int sum = 0;
#pragma unroll
    for (int j = 0; j < 4; ++j) {
        int i = base + j;
        v[j] = (i < NN) ? cnt[i] : 0;
        sum += v[j];
    }
    s[t] = sum;
    __syncthreads();
    for (int off = 1; off < 256; off <<= 1) {
        int val = (t >= off) ? s[t - off] : 0;
        __syncthreads();
        s[t] += val;
        __syncthreads();
    }
    int excl = s[t] - sum;
    int total = s[255];
    if (t == 0) bsum[blockIdx.x] = total;
    int run = excl;
#pragma unroll
    for (int j = 0; j < 4; ++j) {
        int i = base + j;
        if (i < NN) {
            row_ptr[i] = run;
            dinv[i] = rsqrtf((float)(v[j] + 1));
            run += v[j];
        }
    }
}

__global__ void scan_sums_kernel(int* __restrict__ bsum, int* __restrict__ row_ptr) {
    __shared__ int s[64];
    int t = threadIdx.x;
    int v = (t < 49) ? bsum[t] : 0;
    s[t] = v;
    __syncthreads();
    for (int off = 1; off < 64; off <<= 1) {
        int val = (t >= off) ? s[t - off] : 0;
        __syncthreads();
        s[t] += val;
        __syncthreads();
    }
    if (t < 49) bsum[t] = s[t] - v;
    if (t == 63) row_ptr[NN] = s[63];
}

__global__ void scan_add_kernel(int* __restrict__ row_ptr, int* __restrict__ cursor,
                                const int* __restrict__ bsum) {
    int i = blockIdx.x * blockDim.x + threadIdx.x;
    if (i >= NN) return;
    int r = row_ptr[i] + bsum[i >> 10];
    row_ptr[i] = r;
    cursor[i] = r;
}

__global__ void fill_kernel(const int* __restrict__ ei, int* __restrict__ cursor,
                            int* __restrict__ col) {
    int e = blockIdx.x * blockDim.x + threadIdx.x;
    if (e >= NE) return;
    int sidx = ei[e];
    int d = ei[NE + e];
    sidx = min(max(sidx, 0), NN - 1);
    d = min(max(d, 0), NN - 1);
    int pos = atomicAdd(&cursor[d], 1);
    col[pos] = sidx;
}

// ---------------- weight prep: WT1[c][k] = bf16(W1[k][c]), WT2 likewise ----------------

__global__ void prep_wt(const float* __restrict__ W1, const float* __restrict__ W2,
                        ushort* __restrict__ WT1, ushort* __restrict__ WT2) {
    int i = blockIdx.x * blockDim.x + threadIdx.x;
    if (i < KD * HIDD) {
        int c = i / KD, k = i % KD;
        WT1[i] = f2bf(W1[(size_t)k * HIDD + c]);
    } else if (i < KD * HIDD + HIDD * HIDD) {
        int j = i - KD * HIDD;
        int c = j / HIDD, k = j % HIDD;
        WT2[j] = f2bf(W2[(size_t)k * HIDD + c]);
    }
}

// ---------------- MFMA GEMM: out[r][c] = bf16(dinv[r] * sum_k A[r][k] W[k][c]) ----------------
// BM=32, BN=128, BK=64. 1563 blocks, 4 waves (2x2), wave tile 16x64 = 1x4 frags.
// LDS XOR-swizzle on 16B granule: slot g holds source k-group g^(row&7).
// B (and A when bf16) staged via global_load_lds: linear LDS dest (base+lane*16),
// pre-swizzled global source k-group = (lane&7)^(lane>>3)  [rule 21].

template <int KTOT, bool ABF16>
__global__ __launch_bounds__(256) void mfma_gemm(const void* __restrict__ Ap,
                                                 const ushort* __restrict__ WT,
                                                 const float* __restrict__ dinv,
                                                 ushort* __restrict__ out, int M) {
    __shared__ ushort As[32 * 64];
    __shared__ ushort Bs[128 * 64];
    int t = threadIdx.x;
    int lane = t & 63;
    int wid = t >> 6;
    int wr = wid >> 1, wc = wid & 1;
    int row0 = blockIdx.x * 32;
    f32x4 acc[4] = {};

    // per-lane source swizzle for gll chunks: 8 rows x 8 k-groups per 64-lane wave
    int lr = lane >> 3;                 // row-in-chunk 0..7
    int lg = (lane & 7) ^ lr;           // pre-swizzled source k-group

    for (int k0 = 0; k0 < KTOT; k0 += 64) {
        if (ABF16) {
            const ushort* A = (const ushort*)Ap;
            // one 8-row chunk per wave (4 waves x 8 = 32 rows)
            int r = wid * 8 + lr;
            int gr = min(row0 + r, M - 1);
            gll16(&A[(size_t)gr * KTOT + k0 + lg * 8], &As[wid * 8 * 64]);
        } else {
            const float* A = (const float*)Ap;
#pragma unroll
            for (int it = 0; it < 2; ++it) {
                int r = (t >> 4) + it * 16;
                int k4 = t & 15;
                int gr = min(row0 + r, M - 1);
                float4 v = *(const float4*)&A[(size_t)gr * KTOT + k0 + k4 * 4];
                ushort4 w;
                w.x = f2bf(v.x); w.y = f2bf(v.y); w.z = f2bf(v.z); w.w = f2bf(v.w);
                int g = k4 >> 1, half = k4 & 1;
                *(ushort4*)&As[r * 64 + ((g ^ (r & 7)) * 8) + half * 4] = w;
            }
        }
        // B: 16 chunks of 8 cols, 4 per wave
#pragma unroll
        for (int it = 0; it < 4; ++it) {
            int ci = wid * 4 + it;
            int c = ci * 8 + lr;
            gll16(&WT[(size_t)c * KTOT + k0 + lg * 8], &Bs[ci * 512]);
        }
        __syncthreads();
#pragma unroll
        for (int h = 0; h < 2; ++h) {
            int q = h * 4 + (lane >> 4);
            int r = wr * 16 + (lane & 15);
            bf16x8 a = *(const bf16x8*)&As[r * 64 + (q ^ (r & 7)) * 8];
#pragma unroll
            for (int n = 0; n < 4; ++n) {
                int c = wc * 64 + n * 16 + (lane & 15);
                bf16x8 b = *(const bf16x8*)&Bs[c * 64 + (q ^ (c & 7)) * 8];
                acc[n] = __builtin_amdgcn_mfma_f32_16x16x32_bf16(a, b, acc[n], 0, 0, 0);
            }
        }
        __syncthreads();
    }
    // D layout: col=lane&15, row=(lane>>4)*4+reg (m89-verified)
#pragma unroll
    for (int reg = 0; reg < 4; ++reg) {
        int row = row0 + wr * 16 + (lane >> 4) * 4 + reg;
        if (row < M) {
            float d = dinv[row];
#pragma unroll
            for (int n = 0; n < 4; ++n) {
                int colg = wc * 64 + n * 16 + (lane & 15);
                out[(size_t)row * 128 + colg] = f2bf(acc[n][reg] * d);
            }
        }
    }
}

// ---------------- CSR aggregation (bf16 in/out, fp32 accum) ----------------

__global__ void agg_bf_kernel(const ushort* __restrict__ hs, const int* __restrict__ row_ptr,
                              const int* __restrict__ col, const float* __restrict__ dinv,
                              const float* __restrict__ bias, ushort* __restrict__ out) {
    int wv = threadIdx.x >> 6;
    int l = threadIdx.x & 63;
    int i = blockIdx.x * 4 + wv;
    unsigned v0 = *(const unsigned*)&hs[(size_t)i * 128 + 2 * l];
    float ax = bf2f((ushort)(v0 & 0xffff));
    float ay = bf2f((ushort)(v0 >> 16));
    int e0 = row_ptr[i], e1 = row_ptr[i + 1];
    int e = e0;
    for (; e + 4 <= e1; e += 4) {
        int j0 = col[e], j1 = col[e + 1], j2 = col[e + 2], j3 = col[e + 3];
        unsigned w0 = *(const unsigned*)&hs[(size_t)j0 * 128 + 2 * l];
        unsigned w1 = *(const unsigned*)&hs[(size_t)j1 * 128 + 2 * l];
        unsigned w2 = *(const unsigned*)&hs[(size_t)j2 * 128 + 2 * l];
        unsigned w3 = *(const unsigned*)&hs[(size_t)j3 * 128 + 2 * l];
        ax += bf2f((ushort)(w0 & 0xffff)) + bf2f((ushort)(w1 & 0xffff)) +
              bf2f((ushort)(w2 & 0xffff)) + bf2f((ushort)(w3 & 0xffff));
        ay += bf2f((ushort)(w0 >> 16)) + bf2f((ushort)(w1 >> 16)) +
              bf2f((ushort)(w2 >> 16)) + bf2f((ushort)(w3 >> 16));
    }
    for (; e < e1; ++e) {
        int j = col[e];
        unsigned w = *(const unsigned*)&hs[(size_t)j * 128 + 2 * l];
        ax += bf2f((ushort)(w & 0xffff));
        ay += bf2f((ushort)(w >> 16));
    }
    float d = dinv[i];
    float ox = fmaxf(fmaf(ax, d, bias[2 * l]), 0.f);
    float oy = fmaxf(fmaf(ay, d, bias[2 * l + 1]), 0.f);
    unsigned o = (unsigned)f2bf(ox) | ((unsigned)f2bf(oy) << 16);
    *(unsigned*)&out[(size_t)i * 128 + 2 * l] = o;
}

// ---------------- fused agg2 + heads: gather -> relu h2 (regs) -> 12 logits -> log_softmax ----------------

__global__ void agg_heads_kernel(const ushort* __restrict__ hs, const int* __restrict__ row_ptr,
                                 const int* __restrict__ col, const float* __restrict__ dinv,
                                 const float* __restrict__ bias,
                                 const float* __restrict__ Wi, const float* __restrict__ bi,
                                 const float* __restrict__ Wl, const float* __restrict__ bl,
                                 float* __restrict__ out) {
    int wv = threadIdx.x >> 6;
    int l = threadIdx.x & 63;
    int i = blockIdx.x * 4 + wv;
    unsigned v0 = *(const unsigned*)&hs[(size_t)i * 128 + 2 * l];
    float ax = bf2f((ushort)(v0 & 0xffff));
    float ay = bf2f((ushort)(v0 >> 16));
    int e0 = row_ptr[i], e1 = row_ptr[i + 1];
    int e = e0;
    for (; e + 4 <= e1; e += 4) {
        int j0 = col[e], j1 = col[e + 1], j2 = col[e + 2], j3 = col[e + 3];
        unsigned w0 = *(const unsigned*)&hs[(size_t)j0 * 128 + 2 * l];
        unsigned w1 = *(const unsigned*)&hs[(size_t)j1 * 128 + 2 * l];
        unsigned w2 = *(const unsigned*)&hs[(size_t)j2 * 128 + 2 * l];
        unsigned w3 = *(const unsigned*)&hs[(size_t)j3 * 128 + 2 * l];
        ax += bf2f((ushort)(w0 & 0xffff)) + bf2f((ushort)(w1 & 0xffff)) +
              bf2f((ushort)(w2 & 0xffff)) + bf2f((ushort)(w3 & 0xffff));
        ay += bf2f((ushort)(w0 >> 16)) + bf2f((ushort)(w1 >> 16)) +
              bf2f((ushort)(w2 >> 16)) + bf2f((ushort)(w3 >> 16));
    }
    for (; e < e1; ++e) {
        int j = col[e];
        unsigned w = *(const unsigned*)&hs[(size_t)j * 128 + 2 * l];
        ax += bf2f((ushort)(w & 0xffff));
        ay += bf2f((ushort)(w >> 16));
    }
    float d = dinv[i];
    float ox = fmaxf(fmaf(ax, d, bias[2 * l]), 0.f);
    float oy = fmaxf(fmaf(ay, d, bias[2 * l + 1]), 0.f);

    // logits: lane l holds h[2l], h[2l+1]; Wi/Wl are [128][6] row-major
    float4 u0 = *(const float4*)&Wi[l * 12];
    float4 u1 = *(const float4*)&Wi[l * 12 + 4];
    float4 u2 = *(const float4*)&Wi[l * 12 + 8];
    float pi[6];
    pi[0] = ox * u0.x + oy * u1.z;
    pi[1] = ox * u0.y + oy * u1.w;
    pi[2] = ox * u0.z + oy * u2.x;
    pi[3] = ox * u0.w + oy * u2.y;
    pi[4] = ox * u1.x + oy * u2.z;
    pi[5] = ox * u1.y + oy * u2.w;
    u0 = *(const float4*)&Wl[l * 12];
    u1 = *(const float4*)&Wl[l * 12 + 4];
    u2 = *(const float4*)&Wl[l * 12 + 8];
    float pl[6];
    pl[0] = ox * u0.x + oy * u1.z;
    pl[1] = ox * u0.y + oy * u1.w;
    pl[2] = ox * u0.z + oy * u2.x;
    pl[3] = ox * u0.w + oy * u2.y;
    pl[4] = ox * u1.x + oy * u2.z;
    pl[5] = ox * u1.y + oy * u2.w;
#pragma unroll
    for (int off = 1; off < 64; off <<= 1) {
#pragma unroll
        for (int c = 0; c < 6; ++c) {
            pi[c] += __shfl_xor(pi[c], off);
            pl[c] += __shfl_xor(pl[c], off);
        }
    }
#pragma unroll
    for (int c = 0; c < 6; ++c) {
        pi[c] += bi[c];
        pl[c] += bl[c];
    }
    float mi = fmaxf(fmaxf(fmaxf(pi[0], pi[1]), fmaxf(pi[2], pi[3])), fmaxf(pi[4], pi[5]));
    float ml = fmaxf(fmaxf(fmaxf(pl[0], pl[1]), fmaxf(pl[2], pl[3])), fmaxf(pl[4], pl[5]));
    float si = 0.f, sl = 0.f;
#pragma unroll
    for (int c = 0; c < 6; ++c) {
        si += expf(pi[c] - mi);
        sl += expf(pl[c] - ml);
    }
    float lsi = mi + logf(si), lsl = ml + logf(sl);
#pragma unroll
    for (int c = 0; c < 6; ++c) {
        if (l == c)     out[(size_t)i * NC + c] = pi[c] - lsi;
        if (l == 6 + c) out[(size_t)NN * NC + (size_t)i * NC + c] = pl[c] - lsl;
    }
}

extern "C" void kernel_launch(void* const* d_in, const int* in_sizes, int n_in,
                              void* d_out, int out_size, void* d_ws, size_t ws_size,
                              hipStream_t stream) {
    const float* x  = (const float*)d_in[0];
    const int*   ei = (const int*)d_in[1];
    const float* W1 = (const float*)d_in[2];
    const float* b1 = (const float*)d_in[3];
    const float* W2 = (const float*)d_in[4];
    const float* b2 = (const float*)d_in[5];
    const float* Wi = (const float*)d_in[6];
    const float* bi = (const float*)d_in[7];
    const float* Wl = (const float*)d_in[8];
    const float* bl = (const float*)d_in[9];
    float* out = (float*)d_out;

    uint8_t* p = (uint8_t*)d_ws;
    auto alloc = [&](size_t bytes) {
        void* r = (void*)p;
        p += (bytes + 255) / 256 * 256;
        return r;
    };
    int* row_ptr = (int*)alloc((NN + 1) * sizeof(int));
    int* cursor  = (int*)alloc(NN * sizeof(int));
    int* col     = (int*)alloc(NE * sizeof(int));
    int* bsum    = (int*)alloc(64 * sizeof(int));
    float* dinv  = (float*)alloc(NN * sizeof(float));
    ushort* WT1  = (ushort*)alloc((size_t)KD * HIDD * sizeof(ushort));
    ushort* WT2  = (ushort*)alloc((size_t)HIDD * HIDD * sizeof(ushort));
    ushort* bufA = (ushort*)alloc((size_t)NN * HIDD * sizeof(ushort));
    ushort* bufB = (ushort*)alloc((size_t)NN * HIDD * sizeof(ushort));

    hipMemsetAsync(cursor, 0, NN * sizeof(int), stream);
    count_kernel<<<(NE + 255) / 256, 256, 0, stream>>>(ei, cursor);
    scan_blocks_kernel<<<49, 256, 0, stream>>>(cursor, row_ptr, dinv, bsum);
    scan_sums_kernel<<<1, 64, 0, stream>>>(bsum, row_ptr);
    scan_add_kernel<<<(NN + 255) / 256, 256, 0, stream>>>(row_ptr, cursor, bsum);
    fill_kernel<<<(NE + 255) / 256, 256, 0, stream>>>(ei, cursor, col);
    prep_wt<<<(KD * HIDD + HIDD * HIDD + 255) / 256, 256, 0, stream>>>(W1, W2, WT1, WT2);

    const int grid = (NN + 31) / 32;
    // layer 1: hs = bf16(dinv*(x@W1)) ; h1 = bf16(relu(dinv*gather + b1))
    mfma_gemm<KD, false><<<grid, 256, 0, stream>>>(x, WT1, dinv, bufA, NN);
    agg_bf_kernel<<<NN / 4, 256, 0, stream>>>(bufA, row_ptr, col, dinv, b1, bufB);
    // layer 2 + fused heads
    mfma_gemm<HIDD, true><<<grid, 256, 0, stream>>>(bufB, WT2, dinv, bufA, NN);
    agg_heads_kernel<<<NN / 4, 256, 0, stream>>>(bufA, row_ptr, col, dinv, b2,
                                                 Wi, bi, Wl, bl, out);
}

// Round 4
// 230.499 us; speedup vs baseline: 2.6855x; 1.0648x over previous
//
#include <hip/hip_runtime.h>
#include <hip/hip_bf16.h>

#define NN 50000
#define NE 800000
#define KD 768
#define HIDD 128
#define NC 6

typedef __attribute__((ext_vector_type(8))) short bf16x8;
typedef __attribute__((ext_vector_type(4))) float f32x4;

__device__ __forceinline__ ushort f2bf(float f) {
    union { float f; unsigned u; } v; v.f = f;
    unsigned u = v.u + 0x7FFF + ((v.u >> 16) & 1);   // round-to-nearest-even
    return (ushort)(u >> 16);
}
__device__ __forceinline__ float bf2f(ushort h) {
    union { unsigned u; float f; } v; v.u = ((unsigned)h) << 16;
    return v.f;
}
__device__ __forceinline__ void gll16(const void* g, void* l) {
    __builtin_amdgcn_global_load_lds((const __attribute__((address_space(1))) void*)g,
                                     (__attribute__((address_space(3))) void*)l, 16, 0, 0);
}

// ---------------- CSR build ----------------

__global__ void count_kernel(const int* __restrict__ ei, int* __restrict__ cnt) {
    int e = blockIdx.x * blockDim.x + threadIdx.x;
    if (e >= NE) return;
    int d = ei[NE + e];
    d = min(max(d, 0), NN - 1);
    atomicAdd(&cnt[d], 1);
}

__global__ void scan_blocks_kernel(const int* __restrict__ cnt, int* __restrict__ row_ptr,
                                   float* __restrict__ dinv, int* __restrict__ bsum) {
    __shared__ int s[256];
    int t = threadIdx.x;
    int base = blockIdx.x * 1024 + t * 4;
    int v[4];
    int sum = 0;
#pragma unroll
    for (int j = 0; j < 4; ++j) {
        int i = base + j;
        v[j] = (i < NN) ? cnt[i] : 0;
        sum += v[j];
    }
    s[t] = sum;
    __syncthreads();
    for (int off = 1; off < 256; off <<= 1) {
        int val = (t >= off) ? s[t - off] : 0;
        __syncthreads();
        s[t] += val;
        __syncthreads();
    }
    int excl = s[t] - sum;
    int total = s[255];
    if (t == 0) bsum[blockIdx.x] = total;
    int run = excl;
#pragma unroll
    for (int j = 0; j < 4; ++j) {
        int i = base + j;
        if (i < NN) {
            row_ptr[i] = run;
            dinv[i] = rsqrtf((float)(v[j] + 1));
            run += v[j];
        }
    }
}

__global__ void scan_sums_kernel(int* __restrict__ bsum, int* __restrict__ row_ptr) {
    __shared__ int s[64];
    int t = threadIdx.x;
    int v = (t < 49) ? bsum[t] : 0;
    s[t] = v;
    __syncthreads();
    for (int off = 1; off < 64; off <<= 1) {
        int val = (t >= off) ? s[t - off] : 0;
        __syncthreads();
        s[t] += val;
        __syncthreads();
    }
    if (t < 49) bsum[t] = s[t] - v;
    if (t == 63) row_ptr[NN] = s[63];
}

__global__ void scan_add_kernel(int* __restrict__ row_ptr, int* __restrict__ cursor,
                                const int* __restrict__ bsum) {
    int i = blockIdx.x * blockDim.x + threadIdx.x;
    if (i >= NN) return;
    int r = row_ptr[i] + bsum[i >> 10];
    row_ptr[i] = r;
    cursor[i] = r;
}

__global__ void fill_kernel(const int* __restrict__ ei, int* __restrict__ cursor,
                            int* __restrict__ col) {
    int e = blockIdx.x * blockDim.x + threadIdx.x;
    if (e >= NE) return;
    int sidx = ei[e];
    int d = ei[NE + e];
    sidx = min(max(sidx, 0), NN - 1);
    d = min(max(d, 0), NN - 1);
    int pos = atomicAdd(&cursor[d], 1);
    col[pos] = sidx;
}

// ---------------- weight prep: pack B into gll-ready tile order ----------------
// Granule gi within a GEMM's pack: ci (8-col chunk) x ks (K/64 step) x lane.
// lane -> (lr=lane>>3 row-in-chunk, slot=lane&7); slot holds source k-group slot^lr,
// so a linear wave write (dest = base + lane*16B) lands the XOR-swizzled layout.

template <int KTOT>
__device__ __forceinline__ void pack_granule(const float* __restrict__ W,
                                             ushort* __restrict__ WTp, int gi) {
    const int KS = KTOT / 64;
    int ci = gi / (KS * 64);
    int rem = gi % (KS * 64);
    int ks = rem >> 6;
    int lane = rem & 63;
    int lr = lane >> 3;
    int lg = (lane & 7) ^ lr;
    int c = ci * 8 + lr;
    ushort tmp[8];
#pragma unroll
    for (int j = 0; j < 8; ++j)
        tmp[j] = f2bf(W[(size_t)(ks * 64 + lg * 8 + j) * HIDD + c]);
    *(bf16x8*)&WTp[(size_t)gi * 8] = *(bf16x8*)tmp;
}

__global__ void prep_wt_kernel(const float* __restrict__ W1, const float* __restrict__ W2,
                               ushort* __restrict__ WT1p, ushort* __restrict__ WT2p) {
    const int G1 = 16 * (KD / 64) * 64;     // 12288 granules
    const int G2 = 16 * (HIDD / 64) * 64;   // 2048 granules
    int gi = blockIdx.x * blockDim.x + threadIdx.x;
    if (gi < G1) pack_granule<KD>(W1, WT1p, gi);
    else if (gi < G1 + G2) pack_granule<HIDD>(W2, WT2p, gi - G1);
}

// ---------------- MFMA GEMM: out[r][c] = bf16(dinv[r] * sum_k A[r][k] W[k][c]) ----------------
// BM=32, BN=128, BK=64. 4 waves (2x2), wave tile 16x64 = 1x4 frags of 16x16x32.
// B staged via gll from the pre-packed tiles: fully contiguous 1 KB per chunk.

template <int KTOT, bool ABF16>
__global__ __launch_bounds__(256) void mfma_gemm(const void* __restrict__ Ap,
                                                 const ushort* __restrict__ WTp,
                                                 const float* __restrict__ dinv,
                                                 ushort* __restrict__ out, int M) {
    const int KS = KTOT / 64;
    __shared__ ushort As[32 * 64];
    __shared__ ushort Bs[128 * 64];
    int t = threadIdx.x;
    int lane = t & 63;
    int wid = t >> 6;
    int wr = wid >> 1, wc = wid & 1;
    int row0 = blockIdx.x * 32;
    f32x4 acc[4] = {};

    int lr = lane >> 3;                 // row-in-chunk 0..7
    int lg = (lane & 7) ^ lr;           // pre-swizzled source k-group (A path)

    for (int ks = 0; ks < KS; ++ks) {
        int k0 = ks * 64;
        if (ABF16) {
            const ushort* A = (const ushort*)Ap;
            int r = wid * 8 + lr;
            int gr = min(row0 + r, M - 1);
            gll16(&A[(size_t)gr * KTOT + k0 + lg * 8], &As[wid * 8 * 64]);
        } else {
            const float* A = (const float*)Ap;
#pragma unroll
            for (int it = 0; it < 2; ++it) {
                int r = (t >> 4) + it * 16;
                int k4 = t & 15;
                int gr = min(row0 + r, M - 1);
                float4 v = *(const float4*)&A[(size_t)gr * KTOT + k0 + k4 * 4];
                ushort4 w;
                w.x = f2bf(v.x); w.y = f2bf(v.y); w.z = f2bf(v.z); w.w = f2bf(v.w);
                int g = k4 >> 1, half = k4 & 1;
                *(ushort4*)&As[r * 64 + ((g ^ (r & 7)) * 8) + half * 4] = w;
            }
        }
        // B: 16 chunks of 8 cols, 4 per wave — contiguous 1 KB per gll chunk
#pragma unroll
        for (int it = 0; it < 4; ++it) {
            int ci = wid * 4 + it;
            gll16(&WTp[(size_t)((ci * KS + ks) * 64 + lane) * 8], &Bs[ci * 512]);
        }
        __syncthreads();
#pragma unroll
        for (int h = 0; h < 2; ++h) {
            int q = h * 4 + (lane >> 4);
            int r = wr * 16 + (lane & 15);
            bf16x8 a = *(const bf16x8*)&As[r * 64 + (q ^ (r & 7)) * 8];
#pragma unroll
            for (int n = 0; n < 4; ++n) {
                int c = wc * 64 + n * 16 + (lane & 15);
                bf16x8 b = *(const bf16x8*)&Bs[c * 64 + (q ^ (c & 7)) * 8];
                acc[n] = __builtin_amdgcn_mfma_f32_16x16x32_bf16(a, b, acc[n], 0, 0, 0);
            }
        }
        __syncthreads();
    }
    // D layout: col=lane&15, row=(lane>>4)*4+reg (m89-verified)
#pragma unroll
    for (int reg = 0; reg < 4; ++reg) {
        int row = row0 + wr * 16 + (lane >> 4) * 4 + reg;
        if (row < M) {
            float d = dinv[row];
#pragma unroll
            for (int n = 0; n < 4; ++n) {
                int colg = wc * 64 + n * 16 + (lane & 15);
                out[(size_t)row * 128 + colg] = f2bf(acc[n][reg] * d);
            }
        }
    }
}

// ---------------- CSR aggregation (bf16 in/out, fp32 accum), 8-deep gather pipeline ----------------

__device__ __forceinline__ void acc_edge(float& ax, float& ay, unsigned w) {
    ax += bf2f((ushort)(w & 0xffff));
    ay += bf2f((ushort)(w >> 16));
}

__global__ void agg1_kernel(const ushort* __restrict__ hs, const int* __restrict__ row_ptr,
                            const int* __restrict__ col, const float* __restrict__ dinv,
                            const float* __restrict__ bias, ushort* __restrict__ out) {
    int wv = threadIdx.x >> 6;
    int l = threadIdx.x & 63;
    int i = blockIdx.x * 4 + wv;
    unsigned v0 = *(const unsigned*)&hs[(size_t)i * 128 + 2 * l];
    float ax = bf2f((ushort)(v0 & 0xffff));
    float ay = bf2f((ushort)(v0 >> 16));
    int e0 = row_ptr[i], e1 = row_ptr[i + 1];
    int e = e0;
    for (; e + 8 <= e1; e += 8) {
        unsigned w[8];
#pragma unroll
        for (int u = 0; u < 8; ++u)
            w[u] = *(const unsigned*)&hs[(size_t)col[e + u] * 128 + 2 * l];
#pragma unroll
        for (int u = 0; u < 8; ++u) acc_edge(ax, ay, w[u]);
    }
    for (; e + 4 <= e1; e += 4) {
        unsigned w[4];
#pragma unroll
        for (int u = 0; u < 4; ++u)
            w[u] = *(const unsigned*)&hs[(size_t)col[e + u] * 128 + 2 * l];
#pragma unroll
        for (int u = 0; u < 4; ++u) acc_edge(ax, ay, w[u]);
    }
    for (; e < e1; ++e)
        acc_edge(ax, ay, *(const unsigned*)&hs[(size_t)col[e] * 128 + 2 * l]);
    float d = dinv[i];
    float ox = fmaxf(fmaf(ax, d, bias[2 * l]), 0.f);
    float oy = fmaxf(fmaf(ay, d, bias[2 * l + 1]), 0.f);
    unsigned o = (unsigned)f2bf(ox) | ((unsigned)f2bf(oy) << 16);
    *(unsigned*)&out[(size_t)i * 128 + 2 * l] = o;
}

// ---------------- fused agg2 + heads ----------------

__global__ void agg2_heads_kernel(const ushort* __restrict__ hs, const int* __restrict__ row_ptr,
                                  const int* __restrict__ col, const float* __restrict__ dinv,
                                  const float* __restrict__ bias,
                                  const float* __restrict__ Wi, const float* __restrict__ bi,
                                  const float* __restrict__ Wl, const float* __restrict__ bl,
                                  float* __restrict__ out) {
    int wv = threadIdx.x >> 6;
    int l = threadIdx.x & 63;
    int i = blockIdx.x * 4 + wv;
    unsigned v0 = *(const unsigned*)&hs[(size_t)i * 128 + 2 * l];
    float ax = bf2f((ushort)(v0 & 0xffff));
    float ay = bf2f((ushort)(v0 >> 16));
    int e0 = row_ptr[i], e1 = row_ptr[i + 1];
    int e = e0;
    for (; e + 8 <= e1; e += 8) {
        unsigned w[8];
#pragma unroll
        for (int u = 0; u < 8; ++u)
            w[u] = *(const unsigned*)&hs[(size_t)col[e + u] * 128 + 2 * l];
#pragma unroll
        for (int u = 0; u < 8; ++u) acc_edge(ax, ay, w[u]);
    }
    for (; e + 4 <= e1; e += 4) {
        unsigned w[4];
#pragma unroll
        for (int u = 0; u < 4; ++u)
            w[u] = *(const unsigned*)&hs[(size_t)col[e + u] * 128 + 2 * l];
#pragma unroll
        for (int u = 0; u < 4; ++u) acc_edge(ax, ay, w[u]);
    }
    for (; e < e1; ++e)
        acc_edge(ax, ay, *(const unsigned*)&hs[(size_t)col[e] * 128 + 2 * l]);
    float d = dinv[i];
    float ox = fmaxf(fmaf(ax, d, bias[2 * l]), 0.f);
    float oy = fmaxf(fmaf(ay, d, bias[2 * l + 1]), 0.f);

    // logits: lane l holds h[2l], h[2l+1]; Wi/Wl are [128][6] row-major
    float4 u0 = *(const float4*)&Wi[l * 12];
    float4 u1 = *(const float4*)&Wi[l * 12 + 4];
    float4 u2 = *(const float4*)&Wi[l * 12 + 8];
    float pi[6];
    pi[0] = ox * u0.x + oy * u1.z;
    pi[1] = ox * u0.y + oy * u1.w;
    pi[2] = ox * u0.z + oy * u2.x;
    pi[3] = ox * u0.w + oy * u2.y;
    pi[4] = ox * u1.x + oy * u2.z;
    pi[5] = ox * u1.y + oy * u2.w;
    u0 = *(const float4*)&Wl[l * 12];
    u1 = *(const float4*)&Wl[l * 12 + 4];
    u2 = *(const float4*)&Wl[l * 12 + 8];
    float pl[6];
    pl[0] = ox * u0.x + oy * u1.z;
    pl[1] = ox * u0.y + oy * u1.w;
    pl[2] = ox * u0.z + oy * u2.x;
    pl[3] = ox * u0.w + oy * u2.y;
    pl[4] = ox * u1.x + oy * u2.z;
    pl[5] = ox * u1.y + oy * u2.w;
#pragma unroll
    for (int off = 1; off < 64; off <<= 1) {
#pragma unroll
        for (int c = 0; c < 6; ++c) {
            pi[c] += __shfl_xor(pi[c], off);
            pl[c] += __shfl_xor(pl[c], off);
        }
    }
#pragma unroll
    for (int c = 0; c < 6; ++c) {
        pi[c] += bi[c];
        pl[c] += bl[c];
    }
    float mi = fmaxf(fmaxf(fmaxf(pi[0], pi[1]), fmaxf(pi[2], pi[3])), fmaxf(pi[4], pi[5]));
    float ml = fmaxf(fmaxf(fmaxf(pl[0], pl[1]), fmaxf(pl[2], pl[3])), fmaxf(pl[4], pl[5]));
    float si = 0.f, sl = 0.f;
#pragma unroll
    for (int c = 0; c < 6; ++c) {
        si += expf(pi[c] - mi);
        sl += expf(pl[c] - ml);
    }
    float lsi = mi + logf(si), lsl = ml + logf(sl);
#pragma unroll
    for (int c = 0; c < 6; ++c) {
        if (l == c)     out[(size_t)i * NC + c] = pi[c] - lsi;
        if (l == 6 + c) out[(size_t)NN * NC + (size_t)i * NC + c] = pl[c] - lsl;
    }
}

extern "C" void kernel_launch(void* const* d_in, const int* in_sizes, int n_in,
                              void* d_out, int out_size, void* d_ws, size_t ws_size,
                              hipStream_t stream) {
    const float* x  = (const float*)d_in[0];
    const int*   ei = (const int*)d_in[1];
    const float* W1 = (const float*)d_in[2];
    const float* b1 = (const float*)d_in[3];
    const float* W2 = (const float*)d_in[4];
    const float* b2 = (const float*)d_in[5];
    const float* Wi = (const float*)d_in[6];
    const float* bi = (const float*)d_in[7];
    const float* Wl = (const float*)d_in[8];
    const float* bl = (const float*)d_in[9];
    float* out = (float*)d_out;

    uint8_t* p = (uint8_t*)d_ws;
    auto alloc = [&](size_t bytes) {
        void* r = (void*)p;
        p += (bytes + 255) / 256 * 256;
        return r;
    };
    int* row_ptr = (int*)alloc((NN + 1) * sizeof(int));
    int* cursor  = (int*)alloc(NN * sizeof(int));
    int* col     = (int*)alloc(NE * sizeof(int));
    int* bsum    = (int*)alloc(64 * sizeof(int));
    float* dinv  = (float*)alloc(NN * sizeof(float));
    ushort* WT1p = (ushort*)alloc((size_t)KD * HIDD * sizeof(ushort));
    ushort* WT2p = (ushort*)alloc((size_t)HIDD * HIDD * sizeof(ushort));
    ushort* bufA = (ushort*)alloc((size_t)NN * HIDD * sizeof(ushort));
    ushort* bufB = (ushort*)alloc((size_t)NN * HIDD * sizeof(ushort));

    hipMemsetAsync(cursor, 0, NN * sizeof(int), stream);
    count_kernel<<<(NE + 255) / 256, 256, 0, stream>>>(ei, cursor);
    scan_blocks_kernel<<<49, 256, 0, stream>>>(cursor, row_ptr, dinv, bsum);
    scan_sums_kernel<<<1, 64, 0, stream>>>(bsum, row_ptr);
    scan_add_kernel<<<(NN + 255) / 256, 256, 0, stream>>>(row_ptr, cursor, bsum);
    fill_kernel<<<(NE + 255) / 256, 256, 0, stream>>>(ei, cursor, col);
    prep_wt_kernel<<<56, 256, 0, stream>>>(W1, W2, WT1p, WT2p);

    const int grid = (NN + 31) / 32;
    // layer 1: hs = bf16(dinv*(x@W1)) ; h1 = bf16(relu(dinv*gather + b1))
    mfma_gemm<KD, false><<<grid, 256, 0, stream>>>(x, WT1p, dinv, bufA, NN);
    agg1_kernel<<<NN / 4, 256, 0, stream>>>(bufA, row_ptr, col, dinv, b1, bufB);
    // layer 2 + fused heads
    mfma_gemm<HIDD, true><<<grid, 256, 0, stream>>>(bufB, WT2p, dinv, bufA, NN);
    agg2_heads_kernel<<<NN / 4, 256, 0, stream>>>(bufA, row_ptr, col, dinv, b2,
                                                  Wi, bi, Wl, bl, out);
}